// Round 4
// baseline (675.333 us; speedup 1.0000x reference)
//
#include <hip/hip_runtime.h>
#include <hip/hip_bf16.h>
#include <stdint.h>

// ---- problem constants ----
#define D_MODEL 1024
#define SEQ     2048
#define BATCH   4
#define NHEAD   16
#define DKH     64
#define MTOT    (BATCH * SEQ)      // 8192
#define NEG_BIG (-1.0e30f)         // finite "minus infinity" (fast-math safe)

typedef __bf16 bf16x8 __attribute__((ext_vector_type(8)));
typedef float  floatx4 __attribute__((ext_vector_type(4)));

// load 8 consecutive elements as bf16x8 (converting if fp32)
__device__ __forceinline__ bf16x8 load8cvt(const float* p) {
    floatx4 lo = *(const floatx4*)p;
    floatx4 hi = *(const floatx4*)(p + 4);
    bf16x8 r;
    r[0] = (__bf16)lo[0]; r[1] = (__bf16)lo[1];
    r[2] = (__bf16)lo[2]; r[3] = (__bf16)lo[3];
    r[4] = (__bf16)hi[0]; r[5] = (__bf16)hi[1];
    r[6] = (__bf16)hi[2]; r[7] = (__bf16)hi[3];
    return r;
}
__device__ __forceinline__ bf16x8 load8cvt(const __bf16* p) {
    return *(const bf16x8*)p;
}

// ---------------------------------------------------------------------------
// GEMM: out[m,n] = sum_k A[m,k] * (bf16)W[n,k] + bias[n]
// A: [M=8192, K=1024] row-major (fp32 or bf16), W: [1024,1024] fp32.
// Block tile 128x128, BK=32. 4 waves, each 64x64 (4x4 mfma_16x16x32 tiles).
// Staging: global -> regs (+fp32->bf16 cvt) -> ds_write_b128.
// LDS [4 kgroups][128 rows][8]: slot c holds A[m0+(c&127)][k0+(c>>7)*8..+7].
// MODE 0: fp32 out, idx = m*1024 + n
// MODE 1: bf16 out, [b][h][s][d] with m=b*2048+s, n=h*64+d  (QKV layout)
// ---------------------------------------------------------------------------
template<typename TA, int MODE>
__device__ __forceinline__ void gemm_body(const TA* __restrict__ A,
                                          const float* __restrict__ W,
                                          const float* __restrict__ bias,
                                          void* __restrict__ outp)
{
    __shared__ __align__(16) __bf16 As[4][128][8];
    __shared__ __align__(16) __bf16 Bs[4][128][8];

    const int t    = threadIdx.x;
    const int w    = t >> 6;
    const int l    = t & 63;
    const int quad = l >> 4;
    const int r16  = l & 15;
    const int wm   = w & 1;       // wave M-position (2x2 wave grid)
    const int wn   = w >> 1;      // wave N-position
    const int m0   = blockIdx.y * 128;
    const int n0   = blockIdx.x * 128;

    floatx4 acc[4][4];
#pragma unroll
    for (int i = 0; i < 4; ++i)
#pragma unroll
        for (int j = 0; j < 4; ++j) acc[i][j] = (floatx4){0.f, 0.f, 0.f, 0.f};

    // staging: slot c (0..511) -> kgroup = c>>7, row = c&127
    const int c0 = t, c1 = t + 256;
    const TA*    Ag0 = A + (size_t)(m0 + (c0 & 127)) * 1024 + ((c0 >> 7) * 8);
    const TA*    Ag1 = A + (size_t)(m0 + (c1 & 127)) * 1024 + ((c1 >> 7) * 8);
    const float* Wg0 = W + (size_t)(n0 + (c0 & 127)) * 1024 + ((c0 >> 7) * 8);
    const float* Wg1 = W + (size_t)(n0 + (c1 & 127)) * 1024 + ((c1 >> 7) * 8);
    __bf16* sA = &As[0][0][0];
    __bf16* sB = &Bs[0][0][0];

    for (int k0 = 0; k0 < 1024; k0 += 32) {
        bf16x8 ra0 = load8cvt(Ag0 + k0);
        bf16x8 ra1 = load8cvt(Ag1 + k0);
        bf16x8 rb0 = load8cvt(Wg0 + k0);
        bf16x8 rb1 = load8cvt(Wg1 + k0);
        __syncthreads();   // previous iteration's readers done
        *(bf16x8*)(sA + c0 * 8) = ra0;
        *(bf16x8*)(sA + c1 * 8) = ra1;
        *(bf16x8*)(sB + c0 * 8) = rb0;
        *(bf16x8*)(sB + c1 * 8) = rb1;
        __syncthreads();   // staging visible to all waves

        bf16x8 af[4], bfm[4];
#pragma unroll
        for (int i = 0; i < 4; ++i)
            af[i] = *(const bf16x8*)&As[quad][wm * 64 + i * 16 + r16][0];
#pragma unroll
        for (int j = 0; j < 4; ++j)
            bfm[j] = *(const bf16x8*)&Bs[quad][wn * 64 + j * 16 + r16][0];
#pragma unroll
        for (int i = 0; i < 4; ++i)
#pragma unroll
            for (int j = 0; j < 4; ++j)
                acc[i][j] = __builtin_amdgcn_mfma_f32_16x16x32_bf16(
                    af[i], bfm[j], acc[i][j], 0, 0, 0);
    }

    // epilogue: C/D layout row = quad*4 + r, col = r16
#pragma unroll
    for (int i = 0; i < 4; ++i) {
        const int mg = m0 + wm * 64 + i * 16 + quad * 4;
#pragma unroll
        for (int j = 0; j < 4; ++j) {
            const int ng = n0 + wn * 64 + j * 16 + r16;
            const float bb = bias[ng];
#pragma unroll
            for (int r = 0; r < 4; ++r) {
                const int m = mg + r;
                const float v = acc[i][j][r] + bb;
                if (MODE == 0) {
                    ((float*)outp)[(size_t)m * 1024 + ng] = v;
                } else {
                    const int b = m >> 11, s = m & 2047;
                    const int h = ng >> 6, d = ng & 63;
                    const size_t idx = ((size_t)(b * 16 + h) << 17) +
                                       ((size_t)s << 6) + d;
                    ((__bf16*)outp)[idx] = (__bf16)v;
                }
            }
        }
    }
}

__global__ __launch_bounds__(256)
void qkv_gemm_kernel(const float* __restrict__ x,
                     const float* __restrict__ Wq, const float* __restrict__ bq,
                     const float* __restrict__ Wk, const float* __restrict__ bk,
                     const float* __restrict__ Wv, const float* __restrict__ bv,
                     __bf16* __restrict__ Q, __bf16* __restrict__ K,
                     __bf16* __restrict__ V)
{
    const int z = blockIdx.z;
    const float* W  = (z == 0) ? Wq : ((z == 1) ? Wk : Wv);
    const float* bb = (z == 0) ? bq : ((z == 1) ? bk : bv);
    __bf16* out     = (z == 0) ? Q  : ((z == 1) ? K  : V);
    gemm_body<float, 1>(x, W, bb, out);
}

__global__ __launch_bounds__(256)
void out_gemm_kernel(const __bf16* __restrict__ A,
                     const float* __restrict__ Wo, const float* __restrict__ bo,
                     float* __restrict__ out)
{
    gemm_body<__bf16, 0>(A, Wo, bo, out);
}

// ---------------------------------------------------------------------------
// Flash attention, causal. Q,K,V in [B,H,S,64] bf16.
// Block: 256 thr (4 waves), 64 q-rows per block (16 per wave).
// grid = (S/64 = 32, B*H = 64).
// Output written to attn buffer in [B,S,H*64] bf16 (ready for out proj).
// No IEEE infinities anywhere (NEG_BIG). P LDS round-trip barrier-protected.
// ---------------------------------------------------------------------------
__global__ __launch_bounds__(256)
void attn_kernel(const __bf16* __restrict__ Qg, const __bf16* __restrict__ Kg,
                 const __bf16* __restrict__ Vg, __bf16* __restrict__ O)
{
    __shared__ __align__(16) __bf16 Ks[64][72];      // [s][d], +8 pad
    __shared__ __align__(16) __bf16 Vt[64][72];      // [d][s], +8 pad
    __shared__ __align__(16) __bf16 Ps[4][16][72];   // per-wave P, [q][s], +8 pad

    const int t    = threadIdx.x;
    const int w    = t >> 6;
    const int l    = t & 63;
    const int quad = l >> 4;
    const int r16  = l & 15;
    const int qt   = blockIdx.x;          // q-tile 0..31
    const int bh   = blockIdx.y;          // 0..63
    const int q0   = qt * 64;
    const size_t base = (size_t)bh * SEQ * DKH;

    // Q A-fragments (m = r16, k = d): 2 K-steps covering d=0..63
    const int qrow = q0 + w * 16 + r16;
    bf16x8 qf0 = *(const bf16x8*)&Qg[base + (size_t)qrow * 64 + quad * 8];
    bf16x8 qf1 = *(const bf16x8*)&Qg[base + (size_t)qrow * 64 + 32 + quad * 8];

    floatx4 o[4];
#pragma unroll
    for (int j = 0; j < 4; ++j) o[j] = (floatx4){0.f, 0.f, 0.f, 0.f};
    float m_i[4], l_i[4];
#pragma unroll
    for (int r = 0; r < 4; ++r) { m_i[r] = NEG_BIG; l_i[r] = 0.f; }

    for (int kt = 0; kt <= qt; ++kt) {
        __syncthreads();    // prev tile's readers done
        // stage K tile [s][d] and V^T tile [d][s]
#pragma unroll
        for (int it = 0; it < 2; ++it) {
            const int c = it * 256 + t;
            const int row = c >> 3, col8 = (c & 7) * 8;
            const size_t g = base + (size_t)(kt * 64 + row) * 64 + col8;
            bf16x8 kv = *(const bf16x8*)&Kg[g];
            *(bf16x8*)&Ks[row][col8] = kv;
            bf16x8 vv = *(const bf16x8*)&Vg[g];
#pragma unroll
            for (int e = 0; e < 8; ++e) Vt[col8 + e][row] = vv[e];
        }
        __syncthreads();

        // S = Q K^T : B-frags from Ks (n = s-col, k = d)
        floatx4 sc[4];
#pragma unroll
        for (int j = 0; j < 4; ++j) {
            bf16x8 kf0 = *(const bf16x8*)&Ks[j * 16 + r16][quad * 8];
            bf16x8 kf1 = *(const bf16x8*)&Ks[j * 16 + r16][32 + quad * 8];
            floatx4 z = (floatx4){0.f, 0.f, 0.f, 0.f};
            z = __builtin_amdgcn_mfma_f32_16x16x32_bf16(qf0, kf0, z, 0, 0, 0);
            z = __builtin_amdgcn_mfma_f32_16x16x32_bf16(qf1, kf1, z, 0, 0, 0);
            sc[j] = z;
        }

        // scale + causal mask + row-local max (row = quad*4 + r)
        const bool diag = (kt == qt);
        float mloc[4];
#pragma unroll
        for (int r = 0; r < 4; ++r) {
            const int qg_r = q0 + w * 16 + quad * 4 + r;
            float mm = NEG_BIG;
#pragma unroll
            for (int j = 0; j < 4; ++j) {
                float s = sc[j][r] * 0.125f;
                if (diag) {
                    const int kcol = kt * 64 + j * 16 + r16;
                    if (kcol > qg_r) s = NEG_BIG;
                }
                sc[j][r] = s;
                mm = fmaxf(mm, s);
            }
            mloc[r] = mm;
        }
        // reduce max across the 16 lanes sharing these rows
#pragma unroll
        for (int off = 1; off < 16; off <<= 1)
#pragma unroll
            for (int r = 0; r < 4; ++r)
                mloc[r] = fmaxf(mloc[r], __shfl_xor(mloc[r], off, 64));

        float alpha[4], rs[4];
#pragma unroll
        for (int r = 0; r < 4; ++r) {
            const float mn = fmaxf(m_i[r], mloc[r]);
            alpha[r] = __expf(m_i[r] - mn);   // finite-finite; flushes to 0
            m_i[r] = mn;
            float sum = 0.f;
#pragma unroll
            for (int j = 0; j < 4; ++j) {
                const float p = __expf(sc[j][r] - mn);   // finite-finite
                sc[j][r] = p;
                sum += p;
            }
            rs[r] = sum;
        }
#pragma unroll
        for (int off = 1; off < 16; off <<= 1)
#pragma unroll
            for (int r = 0; r < 4; ++r) rs[r] += __shfl_xor(rs[r], off, 64);
#pragma unroll
        for (int r = 0; r < 4; ++r) {
            l_i[r] = l_i[r] * alpha[r] + rs[r];
#pragma unroll
            for (int j = 0; j < 4; ++j) o[j][r] *= alpha[r];
        }

        // P (C-layout) -> LDS -> A-operand layout.
#pragma unroll
        for (int j = 0; j < 4; ++j)
#pragma unroll
            for (int r = 0; r < 4; ++r)
                Ps[w][quad * 4 + r][j * 16 + r16] = (__bf16)sc[j][r];
        __syncthreads();   // HW-level guarantee writes land before reads

        bf16x8 pf0 = *(const bf16x8*)&Ps[w][r16][quad * 8];
        bf16x8 pf1 = *(const bf16x8*)&Ps[w][r16][32 + quad * 8];
#pragma unroll
        for (int jd = 0; jd < 4; ++jd) {
            bf16x8 vf0 = *(const bf16x8*)&Vt[jd * 16 + r16][quad * 8];
            bf16x8 vf1 = *(const bf16x8*)&Vt[jd * 16 + r16][32 + quad * 8];
            o[jd] = __builtin_amdgcn_mfma_f32_16x16x32_bf16(pf0, vf0, o[jd], 0, 0, 0);
            o[jd] = __builtin_amdgcn_mfma_f32_16x16x32_bf16(pf1, vf1, o[jd], 0, 0, 0);
        }
    }

    // epilogue: O /= l_i ; write to [B, S, H*64]
    const int b = bh >> 4, h = bh & 15;
#pragma unroll
    for (int r = 0; r < 4; ++r) {
        const int qg_r = q0 + w * 16 + quad * 4 + r;
        const float inv = 1.f / l_i[r];
#pragma unroll
        for (int jd = 0; jd < 4; ++jd) {
            const int d = jd * 16 + r16;
            const size_t idx = ((size_t)(b * SEQ + qg_r) * D_MODEL) + h * 64 + d;
            O[idx] = (__bf16)(o[jd][r] * inv);
        }
    }
}

// ---------------------------------------------------------------------------
extern "C" void kernel_launch(void* const* d_in, const int* in_sizes, int n_in,
                              void* d_out, int out_size, void* d_ws, size_t ws_size,
                              hipStream_t stream)
{
    (void)in_sizes; (void)n_in; (void)out_size; (void)ws_size;
    // Inputs are FP32 (per reference setup_inputs); output FP32.
    const float* x  = (const float*)d_in[0];
    const float* Wq = (const float*)d_in[1];
    const float* bq = (const float*)d_in[2];
    const float* Wk = (const float*)d_in[3];
    const float* bk = (const float*)d_in[4];
    const float* Wv = (const float*)d_in[5];
    const float* bv = (const float*)d_in[6];
    const float* Wo = (const float*)d_in[7];
    const float* bo = (const float*)d_in[8];
    float* out = (float*)d_out;

    const size_t n_elem = (size_t)MTOT * D_MODEL;   // 8192*1024
    // Q (bf16, 16MB) parks in d_out (fp32, 32MB; dead after attn).
    // ws: K, V, attn-out — 3 x 16MB bf16 = 48MB.
    __bf16* Qb = (__bf16*)d_out;
    __bf16* Kb = (__bf16*)d_ws;
    __bf16* Vb = Kb + n_elem;
    __bf16* Ab = Vb + n_elem;

    qkv_gemm_kernel<<<dim3(8, 64, 3), 256, 0, stream>>>(x, Wq, bq, Wk, bk, Wv, bv,
                                                        Qb, Kb, Vb);
    attn_kernel<<<dim3(32, 64), 256, 0, stream>>>(Qb, Kb, Vb, Ab);
    out_gemm_kernel<<<dim3(8, 64), 256, 0, stream>>>(Ab, Wo, bo, out);
}

// Round 5
// 532.313 us; speedup vs baseline: 1.2687x; 1.2687x over previous
//
#include <hip/hip_runtime.h>
#include <hip/hip_bf16.h>
#include <stdint.h>

// ---- problem constants ----
#define D_MODEL 1024
#define SEQ     2048
#define BATCH   4
#define NHEAD   16
#define DKH     64
#define MTOT    (BATCH * SEQ)      // 8192
#define NEG_BIG (-1.0e30f)

typedef __bf16 bf16x8 __attribute__((ext_vector_type(8)));
typedef __bf16 bf16x4 __attribute__((ext_vector_type(4)));
typedef float  floatx4 __attribute__((ext_vector_type(4)));

#define GLOAD_LDS16(gp, lp)                                            \
    __builtin_amdgcn_global_load_lds(                                  \
        (const __attribute__((address_space(1))) unsigned int*)(gp),   \
        (__attribute__((address_space(3))) unsigned int*)(lp), 16, 0, 0)

#define MFMA16(a, b, c) __builtin_amdgcn_mfma_f32_16x16x32_bf16(a, b, c, 0, 0, 0)

__device__ __forceinline__ bf16x8 cvt8(floatx4 a, floatx4 b) {
    bf16x8 r;
    r[0] = (__bf16)a[0]; r[1] = (__bf16)a[1]; r[2] = (__bf16)a[2]; r[3] = (__bf16)a[3];
    r[4] = (__bf16)b[0]; r[5] = (__bf16)b[1]; r[6] = (__bf16)b[2]; r[7] = (__bf16)b[3];
    return r;
}

// ---------------------------------------------------------------------------
// fp32 -> bf16 elementwise convert (for weight matrices; n multiple of 4)
// ---------------------------------------------------------------------------
__global__ __launch_bounds__(256)
void cvt_kernel(const float* __restrict__ src, __bf16* __restrict__ dst, int n)
{
    const int i = (blockIdx.x * 256 + threadIdx.x) * 4;
    if (i >= n) return;
    floatx4 v = *(const floatx4*)(src + i);
    bf16x4 o;
    o[0] = (__bf16)v[0]; o[1] = (__bf16)v[1]; o[2] = (__bf16)v[2]; o[3] = (__bf16)v[3];
    *(bf16x4*)(dst + i) = o;
}

// ---------------------------------------------------------------------------
// QKV GEMM: out[m,n] = sum_k (bf16)x[m,k] * Wb[n,k] + bias[n]
// x fp32 [8192,1024]; Wb bf16 [1024,1024] (pre-converted).
// 128x128 tile, BK=32, 4 waves x 64x64. LDS flat [128][32] bf16 (8KB each).
// A: coalesced fp32 loads (64B/lane) + cvt + ds_write_b128.
// B: global_load_lds width=16; slot c -> row c>>2, kgrp c&3 (LDS byte = c*16
//    == (row*32 + kgrp*8) elems, matching the wave-uniform+lane*16 rule).
// Frag reads As[(row)*32 + quad*8]: bank-even, conflict-free.
// Epilogue: Q/K/V written [B,H,S,64] bf16.
// ---------------------------------------------------------------------------
__global__ __launch_bounds__(256)
void qkv_gemm_kernel(const float* __restrict__ x,
                     const __bf16* __restrict__ Wqb, const float* __restrict__ bq,
                     const __bf16* __restrict__ Wkb, const float* __restrict__ bk,
                     const __bf16* __restrict__ Wvb, const float* __restrict__ bv,
                     __bf16* __restrict__ Q, __bf16* __restrict__ K,
                     __bf16* __restrict__ V)
{
    __shared__ __align__(16) __bf16 As[128 * 32];
    __shared__ __align__(16) __bf16 Bs[128 * 32];

    const int z = blockIdx.z;
    const __bf16* Wb   = (z == 0) ? Wqb : ((z == 1) ? Wkb : Wvb);
    const float*  bias = (z == 0) ? bq  : ((z == 1) ? bk  : bv);
    __bf16*       out  = (z == 0) ? Q   : ((z == 1) ? K   : V);

    const int t    = threadIdx.x;
    const int w    = t >> 6, l = t & 63, quad = l >> 4, r16 = l & 15;
    const int wm   = w & 1, wn = w >> 1;
    const int m0   = blockIdx.y * 128;
    const int n0   = blockIdx.x * 128;

    floatx4 acc[4][4];
#pragma unroll
    for (int i = 0; i < 4; ++i)
#pragma unroll
        for (int j = 0; j < 4; ++j) acc[i][j] = (floatx4){0.f, 0.f, 0.f, 0.f};

    const int arow = t >> 1, ahalf = t & 1;           // A: 64B contiguous/lane
    const float* Agp = x + (size_t)(m0 + arow) * 1024 + ahalf * 16;
    const int c0 = t, c1 = t + 256;                   // B slots
    const __bf16* Bg0 = Wb + (size_t)(n0 + (c0 >> 2)) * 1024 + (c0 & 3) * 8;
    const __bf16* Bg1 = Wb + (size_t)(n0 + (c1 >> 2)) * 1024 + (c1 & 3) * 8;
    unsigned int* lBs = (unsigned int*)Bs;

    for (int k0 = 0; k0 < 1024; k0 += 32) {
        floatx4 f0 = *(const floatx4*)(Agp + k0);
        floatx4 f1 = *(const floatx4*)(Agp + k0 + 4);
        floatx4 f2 = *(const floatx4*)(Agp + k0 + 8);
        floatx4 f3 = *(const floatx4*)(Agp + k0 + 12);
        bf16x8 alo = cvt8(f0, f1), ahi = cvt8(f2, f3);
        __syncthreads();   // previous iteration's readers done
        *(bf16x8*)&As[arow * 32 + ahalf * 16]     = alo;
        *(bf16x8*)&As[arow * 32 + ahalf * 16 + 8] = ahi;
        GLOAD_LDS16(Bg0 + k0, lBs + c0 * 4);
        GLOAD_LDS16(Bg1 + k0, lBs + c1 * 4);
        __syncthreads();   // vmcnt drained before barrier -> staging visible

        bf16x8 af[4], bfm[4];
#pragma unroll
        for (int i = 0; i < 4; ++i)
            af[i] = *(const bf16x8*)&As[(wm * 64 + i * 16 + r16) * 32 + quad * 8];
#pragma unroll
        for (int j = 0; j < 4; ++j)
            bfm[j] = *(const bf16x8*)&Bs[(wn * 64 + j * 16 + r16) * 32 + quad * 8];
#pragma unroll
        for (int i = 0; i < 4; ++i)
#pragma unroll
            for (int j = 0; j < 4; ++j)
                acc[i][j] = MFMA16(af[i], bfm[j], acc[i][j]);
    }

    // epilogue: C/D row = quad*4 + r, col = r16 ; out [B,H,S,64]
#pragma unroll
    for (int i = 0; i < 4; ++i) {
        const int mg = m0 + wm * 64 + i * 16 + quad * 4;
#pragma unroll
        for (int j = 0; j < 4; ++j) {
            const int ng = n0 + wn * 64 + j * 16 + r16;
            const float bb = bias[ng];
#pragma unroll
            for (int r = 0; r < 4; ++r) {
                const int m = mg + r;
                const int b = m >> 11, s = m & 2047;
                const int h = ng >> 6, d = ng & 63;
                const size_t idx = ((size_t)(b * 16 + h) << 17) +
                                   ((size_t)s << 6) + d;
                out[idx] = (__bf16)(acc[i][j][r] + bb);
            }
        }
    }
}

// ---------------------------------------------------------------------------
// Output GEMM: out[m,n] = sum_k A[m,k]*Wob[n,k] + bo[n], both bf16, out fp32.
// Full m97 structure: both sides via global_load_lds width=16.
// ---------------------------------------------------------------------------
__global__ __launch_bounds__(256)
void out_gemm_kernel(const __bf16* __restrict__ A, const __bf16* __restrict__ Wob,
                     const float* __restrict__ bo, float* __restrict__ out)
{
    __shared__ __align__(16) __bf16 As[128 * 32];
    __shared__ __align__(16) __bf16 Bs[128 * 32];

    const int t    = threadIdx.x;
    const int w    = t >> 6, l = t & 63, quad = l >> 4, r16 = l & 15;
    const int wm   = w & 1, wn = w >> 1;
    const int m0   = blockIdx.y * 128;
    const int n0   = blockIdx.x * 128;

    floatx4 acc[4][4];
#pragma unroll
    for (int i = 0; i < 4; ++i)
#pragma unroll
        for (int j = 0; j < 4; ++j) acc[i][j] = (floatx4){0.f, 0.f, 0.f, 0.f};

    const int c0 = t, c1 = t + 256;
    const __bf16* Ag0 = A   + (size_t)(m0 + (c0 >> 2)) * 1024 + (c0 & 3) * 8;
    const __bf16* Ag1 = A   + (size_t)(m0 + (c1 >> 2)) * 1024 + (c1 & 3) * 8;
    const __bf16* Bg0 = Wob + (size_t)(n0 + (c0 >> 2)) * 1024 + (c0 & 3) * 8;
    const __bf16* Bg1 = Wob + (size_t)(n0 + (c1 >> 2)) * 1024 + (c1 & 3) * 8;
    unsigned int* lAs = (unsigned int*)As;
    unsigned int* lBs = (unsigned int*)Bs;

    for (int k0 = 0; k0 < 1024; k0 += 32) {
        __syncthreads();
        GLOAD_LDS16(Ag0 + k0, lAs + c0 * 4);
        GLOAD_LDS16(Ag1 + k0, lAs + c1 * 4);
        GLOAD_LDS16(Bg0 + k0, lBs + c0 * 4);
        GLOAD_LDS16(Bg1 + k0, lBs + c1 * 4);
        __syncthreads();

        bf16x8 af[4], bfm[4];
#pragma unroll
        for (int i = 0; i < 4; ++i)
            af[i] = *(const bf16x8*)&As[(wm * 64 + i * 16 + r16) * 32 + quad * 8];
#pragma unroll
        for (int j = 0; j < 4; ++j)
            bfm[j] = *(const bf16x8*)&Bs[(wn * 64 + j * 16 + r16) * 32 + quad * 8];
#pragma unroll
        for (int i = 0; i < 4; ++i)
#pragma unroll
            for (int j = 0; j < 4; ++j)
                acc[i][j] = MFMA16(af[i], bfm[j], acc[i][j]);
    }

#pragma unroll
    for (int i = 0; i < 4; ++i) {
        const int mg = m0 + wm * 64 + i * 16 + quad * 4;
#pragma unroll
        for (int j = 0; j < 4; ++j) {
            const int ng = n0 + wn * 64 + j * 16 + r16;
            const float bb = bo[ng];
#pragma unroll
            for (int r = 0; r < 4; ++r)
                out[(size_t)(mg + r) * 1024 + ng] = acc[i][j][r] + bb;
        }
    }
}

// ---------------------------------------------------------------------------
// Flash attention v2, causal. Q,K,V in [B,H,S,64] bf16.
// 128 q-rows/block, 4 waves x 32 rows (2 m-frags), k-tiles of 64.
// grid = (16, 64); heavy q-tiles first (qt = 15 - bx).
// XOR-swizzled LDS (natural strides, phys 8-elem block = blk ^ f(row)):
//   Ks[64][64]  K[s][d]:   phys = s*64 + ((dblk ^ (s&7))<<3) + (d&7)
//   Vt[64][64]  V^T[d][s]: phys = d*64 + ((sblk ^ (d>>3))<<3) + (s&7)
//   Ps[4][32][64] P[q][s]: phys = q*64 + ((sblk ^ swzp(q))<<3) + (s&7),
//     swzp(q) = (q ^ (q>>3)) & 7
// All b128 accesses 16B aligned; every pattern verified <=2-way on banks.
// ---------------------------------------------------------------------------
__global__ __launch_bounds__(256)
void attn_kernel(const __bf16* __restrict__ Qg, const __bf16* __restrict__ Kg,
                 const __bf16* __restrict__ Vg, __bf16* __restrict__ O)
{
    __shared__ __align__(16) __bf16 Ks[64 * 64];
    __shared__ __align__(16) __bf16 Vt[64 * 64];
    __shared__ __align__(16) __bf16 Ps[4 * 32 * 64];

    const int t    = threadIdx.x;
    const int w    = t >> 6, l = t & 63, quad = l >> 4, r16 = l & 15;
    const int qt   = (int)gridDim.x - 1 - (int)blockIdx.x;  // heavy first
    const int bh   = blockIdx.y;
    const int q0   = qt * 128;
    const size_t base = (size_t)bh * SEQ * DKH;
    __bf16* Pw = &Ps[w * 32 * 64];

    // Q A-frags: 2 m-tiles x 2 k-steps
    bf16x8 qf[2][2];
#pragma unroll
    for (int mi = 0; mi < 2; ++mi) {
        const int row = q0 + w * 32 + mi * 16 + r16;
        qf[mi][0] = *(const bf16x8*)&Qg[base + (size_t)row * 64 + quad * 8];
        qf[mi][1] = *(const bf16x8*)&Qg[base + (size_t)row * 64 + 32 + quad * 8];
    }

    floatx4 o[2][4];
    float m_i[2][4], l_i[2][4];
#pragma unroll
    for (int mi = 0; mi < 2; ++mi)
#pragma unroll
        for (int j = 0; j < 4; ++j) {
            o[mi][j] = (floatx4){0.f, 0.f, 0.f, 0.f};
            m_i[mi][j] = NEG_BIG; l_i[mi][j] = 0.f;
        }

    const int prow0 = r16, psw0 = (prow0 ^ (prow0 >> 3)) & 7;
    const int prow1 = 16 + r16, psw1 = (prow1 ^ (prow1 >> 3)) & 7;
    const int wrow0 = q0 + w * 32;

    const int nkt = 2 * qt + 2;
    for (int kt = 0; kt < nkt; ++kt) {
        __syncthreads();   // prev tile readers done
        // stage K [s][d] and V^T [d][s], swizzled
#pragma unroll
        for (int it = 0; it < 2; ++it) {
            const int c = it * 256 + t;
            const int s = c >> 3, g = c & 7;
            const size_t gofs = base + (size_t)(kt * 64 + s) * 64 + g * 8;
            bf16x8 kv = *(const bf16x8*)&Kg[gofs];
            *(bf16x8*)&Ks[s * 64 + ((g ^ (s & 7)) << 3)] = kv;
            bf16x8 vv = *(const bf16x8*)&Vg[gofs];
            const int sb = s >> 3, s7 = s & 7;
#pragma unroll
            for (int e = 0; e < 8; ++e) {
                const int d = g * 8 + e;               // d>>3 == g
                Vt[d * 64 + ((sb ^ g) << 3) + s7] = vv[e];
            }
        }
        __syncthreads();

        const bool active = (kt * 64 <= wrow0 + 31);   // wave-uniform
        if (active) {
            // K B-frags (shared by both mi)
            bf16x8 kf[4][2];
#pragma unroll
            for (int j = 0; j < 4; ++j) {
                const int sc_ = j * 16 + r16, s7 = sc_ & 7;
                kf[j][0] = *(const bf16x8*)&Ks[sc_ * 64 + ((quad ^ s7) << 3)];
                kf[j][1] = *(const bf16x8*)&Ks[sc_ * 64 + (((4 + quad) ^ s7) << 3)];
            }
#pragma unroll
            for (int mi = 0; mi < 2; ++mi) {
                const int rmin = wrow0 + mi * 16;
                if (kt * 64 > rmin + 15) continue;     // fully masked (uniform)
                floatx4 sc[4];
#pragma unroll
                for (int j = 0; j < 4; ++j) {
                    floatx4 z = (floatx4){0.f, 0.f, 0.f, 0.f};
                    z = MFMA16(qf[mi][0], kf[j][0], z);
                    z = MFMA16(qf[mi][1], kf[j][1], z);
                    sc[j] = z;
                }
                const bool diag = (kt * 64 + 63 > rmin);
                float mloc[4];
#pragma unroll
                for (int r = 0; r < 4; ++r) {
                    const int qg_r = rmin + quad * 4 + r;
                    float mm = NEG_BIG;
#pragma unroll
                    for (int j = 0; j < 4; ++j) {
                        float s = sc[j][r] * 0.125f;
                        if (diag && (kt * 64 + j * 16 + r16 > qg_r)) s = NEG_BIG;
                        sc[j][r] = s;
                        mm = fmaxf(mm, s);
                    }
                    mloc[r] = mm;
                }
#pragma unroll
                for (int off = 1; off < 16; off <<= 1)
#pragma unroll
                    for (int r = 0; r < 4; ++r)
                        mloc[r] = fmaxf(mloc[r], __shfl_xor(mloc[r], off, 64));
                float rs[4];
#pragma unroll
                for (int r = 0; r < 4; ++r) {
                    const float mn = fmaxf(m_i[mi][r], mloc[r]);
                    const float alpha = __expf(m_i[mi][r] - mn);
                    m_i[mi][r] = mn;
                    float sum = 0.f;
#pragma unroll
                    for (int j = 0; j < 4; ++j) {
                        const float p = __expf(sc[j][r] - mn);
                        sc[j][r] = p;
                        sum += p;
                    }
                    rs[r] = sum;
                    l_i[mi][r] *= alpha;
#pragma unroll
                    for (int j = 0; j < 4; ++j) o[mi][j][r] *= alpha;
                }
#pragma unroll
                for (int off = 1; off < 16; off <<= 1)
#pragma unroll
                    for (int r = 0; r < 4; ++r) rs[r] += __shfl_xor(rs[r], off, 64);
#pragma unroll
                for (int r = 0; r < 4; ++r) l_i[mi][r] += rs[r];

                // P store (C-layout -> swizzled A-layout region)
#pragma unroll
                for (int j = 0; j < 4; ++j) {
                    const int blk = 2 * j + (r16 >> 3), c7 = r16 & 7;
#pragma unroll
                    for (int r = 0; r < 4; ++r) {
                        const int row = mi * 16 + quad * 4 + r;
                        const int sw = (row ^ (row >> 3)) & 7;
                        Pw[row * 64 + ((blk ^ sw) << 3) + c7] = (__bf16)sc[j][r];
                    }
                }
            }
        }
        __syncthreads();   // P visible (HW ordering)
        if (active) {
#pragma unroll
            for (int mi = 0; mi < 2; ++mi) {
                if (kt * 64 > wrow0 + mi * 16 + 15) continue;
                const int prow = mi ? prow1 : prow0;
                const int psw  = mi ? psw1  : psw0;
                bf16x8 pf0 = *(const bf16x8*)&Pw[prow * 64 + ((quad ^ psw) << 3)];
                bf16x8 pf1 = *(const bf16x8*)&Pw[prow * 64 + (((4 + quad) ^ psw) << 3)];
#pragma unroll
                for (int jd = 0; jd < 4; ++jd) {
                    const int d = jd * 16 + r16, db = d >> 3;
                    bf16x8 vf0 = *(const bf16x8*)&Vt[d * 64 + ((quad ^ db) << 3)];
                    bf16x8 vf1 = *(const bf16x8*)&Vt[d * 64 + (((4 + quad) ^ db) << 3)];
                    o[mi][jd] = MFMA16(pf0, vf0, o[mi][jd]);
                    o[mi][jd] = MFMA16(pf1, vf1, o[mi][jd]);
                }
            }
        }
    }

    // epilogue: O /= l ; write [B,S,H*64] bf16
    const int b = bh >> 4, h = bh & 15;
#pragma unroll
    for (int mi = 0; mi < 2; ++mi)
#pragma unroll
        for (int r = 0; r < 4; ++r) {
            const int row = wrow0 + mi * 16 + quad * 4 + r;
            const float inv = 1.f / l_i[mi][r];
#pragma unroll
            for (int jd = 0; jd < 4; ++jd) {
                const int d = jd * 16 + r16;
                O[((size_t)(b * SEQ + row) * D_MODEL) + h * 64 + d] =
                    (__bf16)(o[mi][jd][r] * inv);
            }
        }
}

// ---------------------------------------------------------------------------
extern "C" void kernel_launch(void* const* d_in, const int* in_sizes, int n_in,
                              void* d_out, int out_size, void* d_ws, size_t ws_size,
                              hipStream_t stream)
{
    (void)in_sizes; (void)n_in; (void)out_size; (void)ws_size;
    const float* x  = (const float*)d_in[0];
    const float* Wq = (const float*)d_in[1];
    const float* bq = (const float*)d_in[2];
    const float* Wk = (const float*)d_in[3];
    const float* bk = (const float*)d_in[4];
    const float* Wv = (const float*)d_in[5];
    const float* bv = (const float*)d_in[6];
    const float* Wo = (const float*)d_in[7];
    const float* bo = (const float*)d_in[8];
    float* out = (float*)d_out;

    const size_t n_elem = (size_t)MTOT * D_MODEL;       // 8388608
    const int    w_n    = D_MODEL * D_MODEL;            // 1048576
    // d_out (33.5MB fp32) doubles as scratch until the final GEMM:
    //   [0, n_elem) bf16          : Q  (dead after attn)
    //   [n_elem, n_elem+3M) bf16  : Wqb/Wkb/Wvb (dead after qkv)
    __bf16* Qb  = (__bf16*)d_out;
    __bf16* Wqb = (__bf16*)d_out + n_elem;
    __bf16* Wkb = Wqb + w_n;
    __bf16* Wvb = Wkb + w_n;
    // ws (48MB, proven): K, V, attn-out; Wob overlays dead K after attn.
    __bf16* Kb  = (__bf16*)d_ws;
    __bf16* Vb  = Kb + n_elem;
    __bf16* Ab  = Vb + n_elem;
    __bf16* Wob = Kb;

    cvt_kernel<<<w_n / 1024, 256, 0, stream>>>(Wq, Wqb, w_n);
    cvt_kernel<<<w_n / 1024, 256, 0, stream>>>(Wk, Wkb, w_n);
    cvt_kernel<<<w_n / 1024, 256, 0, stream>>>(Wv, Wvb, w_n);
    qkv_gemm_kernel<<<dim3(8, 64, 3), 256, 0, stream>>>(
        x, Wqb, bq, Wkb, bk, Wvb, bv, Qb, Kb, Vb);
    attn_kernel<<<dim3(16, 64), 256, 0, stream>>>(Qb, Kb, Vb, Ab);
    cvt_kernel<<<w_n / 1024, 256, 0, stream>>>(Wo, Wob, w_n);
    out_gemm_kernel<<<dim3(8, 64), 256, 0, stream>>>(Ab, Wob, bo, out);
}

// Round 6
// 401.527 us; speedup vs baseline: 1.6819x; 1.3257x over previous
//
#include <hip/hip_runtime.h>
#include <hip/hip_bf16.h>
#include <stdint.h>

// ---- problem constants ----
#define D_MODEL 1024
#define SEQ     2048
#define BATCH   4
#define NHEAD   16
#define DKH     64
#define MTOT    (BATCH * SEQ)      // 8192

typedef __bf16 bf16x8 __attribute__((ext_vector_type(8)));
typedef __bf16 bf16x4 __attribute__((ext_vector_type(4)));
typedef float  floatx4 __attribute__((ext_vector_type(4)));

#define GLOAD_LDS16(gp, lp)                                            \
    __builtin_amdgcn_global_load_lds(                                  \
        (const __attribute__((address_space(1))) unsigned int*)(gp),   \
        (__attribute__((address_space(3))) unsigned int*)(lp), 16, 0, 0)

#define MFMA16(a, b, c) __builtin_amdgcn_mfma_f32_16x16x32_bf16(a, b, c, 0, 0, 0)

__device__ __forceinline__ bf16x8 cvt8(floatx4 a, floatx4 b) {
    bf16x8 r;
    r[0] = (__bf16)a[0]; r[1] = (__bf16)a[1]; r[2] = (__bf16)a[2]; r[3] = (__bf16)a[3];
    r[4] = (__bf16)b[0]; r[5] = (__bf16)b[1]; r[6] = (__bf16)b[2]; r[7] = (__bf16)b[3];
    return r;
}

// ---------------------------------------------------------------------------
// fp32 -> bf16 elementwise convert (weights)
// ---------------------------------------------------------------------------
__global__ __launch_bounds__(256)
void cvt_kernel(const float* __restrict__ src, __bf16* __restrict__ dst, int n)
{
    const int i = (blockIdx.x * 256 + threadIdx.x) * 4;
    if (i >= n) return;
    floatx4 v = *(const floatx4*)(src + i);
    bf16x4 o;
    o[0] = (__bf16)v[0]; o[1] = (__bf16)v[1]; o[2] = (__bf16)v[2]; o[3] = (__bf16)v[3];
    *(bf16x4*)(dst + i) = o;
}

// ---------------------------------------------------------------------------
// QKV GEMM (unchanged structure from round 5, except V written TRANSPOSED:
// V^T[b,h,d,s] so the attention kernel can stage it with b128 writes).
// ---------------------------------------------------------------------------
__global__ __launch_bounds__(256)
void qkv_gemm_kernel(const float* __restrict__ x,
                     const __bf16* __restrict__ Wqb, const float* __restrict__ bq,
                     const __bf16* __restrict__ Wkb, const float* __restrict__ bk,
                     const __bf16* __restrict__ Wvb, const float* __restrict__ bv,
                     __bf16* __restrict__ Q, __bf16* __restrict__ K,
                     __bf16* __restrict__ V)
{
    __shared__ __align__(16) __bf16 As[128 * 32];
    __shared__ __align__(16) __bf16 Bs[128 * 32];

    const int z = blockIdx.z;
    const __bf16* Wb   = (z == 0) ? Wqb : ((z == 1) ? Wkb : Wvb);
    const float*  bias = (z == 0) ? bq  : ((z == 1) ? bk  : bv);
    __bf16*       out  = (z == 0) ? Q   : ((z == 1) ? K   : V);

    const int t    = threadIdx.x;
    const int w    = t >> 6, l = t & 63, quad = l >> 4, r16 = l & 15;
    const int wm   = w & 1, wn = w >> 1;
    const int m0   = blockIdx.y * 128;
    const int n0   = blockIdx.x * 128;

    floatx4 acc[4][4];
#pragma unroll
    for (int i = 0; i < 4; ++i)
#pragma unroll
        for (int j = 0; j < 4; ++j) acc[i][j] = (floatx4){0.f, 0.f, 0.f, 0.f};

    const int arow = t >> 1, ahalf = t & 1;
    const float* Agp = x + (size_t)(m0 + arow) * 1024 + ahalf * 16;
    const int c0 = t, c1 = t + 256;
    const __bf16* Bg0 = Wb + (size_t)(n0 + (c0 >> 2)) * 1024 + (c0 & 3) * 8;
    const __bf16* Bg1 = Wb + (size_t)(n0 + (c1 >> 2)) * 1024 + (c1 & 3) * 8;
    unsigned int* lBs = (unsigned int*)Bs;

    for (int k0 = 0; k0 < 1024; k0 += 32) {
        floatx4 f0 = *(const floatx4*)(Agp + k0);
        floatx4 f1 = *(const floatx4*)(Agp + k0 + 4);
        floatx4 f2 = *(const floatx4*)(Agp + k0 + 8);
        floatx4 f3 = *(const floatx4*)(Agp + k0 + 12);
        bf16x8 alo = cvt8(f0, f1), ahi = cvt8(f2, f3);
        __syncthreads();
        *(bf16x8*)&As[arow * 32 + ahalf * 16]     = alo;
        *(bf16x8*)&As[arow * 32 + ahalf * 16 + 8] = ahi;
        GLOAD_LDS16(Bg0 + k0, lBs + c0 * 4);
        GLOAD_LDS16(Bg1 + k0, lBs + c1 * 4);
        __syncthreads();

        bf16x8 af[4], bfm[4];
#pragma unroll
        for (int i = 0; i < 4; ++i)
            af[i] = *(const bf16x8*)&As[(wm * 64 + i * 16 + r16) * 32 + quad * 8];
#pragma unroll
        for (int j = 0; j < 4; ++j)
            bfm[j] = *(const bf16x8*)&Bs[(wn * 64 + j * 16 + r16) * 32 + quad * 8];
#pragma unroll
        for (int i = 0; i < 4; ++i)
#pragma unroll
            for (int j = 0; j < 4; ++j)
                acc[i][j] = MFMA16(af[i], bfm[j], acc[i][j]);
    }

#pragma unroll
    for (int i = 0; i < 4; ++i) {
        const int mg = m0 + wm * 64 + i * 16 + quad * 4;
#pragma unroll
        for (int j = 0; j < 4; ++j) {
            const int ng = n0 + wn * 64 + j * 16 + r16;
            const float bb = bias[ng];
#pragma unroll
            for (int r = 0; r < 4; ++r) {
                const int m = mg + r;
                const int b = m >> 11, s = m & 2047;
                const int h = ng >> 6, d = ng & 63;
                size_t idx;
                if (z == 2)   // V^T: [b,h,d,s]
                    idx = ((size_t)((b * 16 + h) * 64 + d) << 11) + s;
                else          // [b,h,s,d]
                    idx = ((size_t)(b * 16 + h) << 17) + ((size_t)s << 6) + d;
                out[idx] = (__bf16)(acc[i][j][r] + bb);
            }
        }
    }
}

// ---------------------------------------------------------------------------
// Output GEMM (unchanged from round 5)
// ---------------------------------------------------------------------------
__global__ __launch_bounds__(256)
void out_gemm_kernel(const __bf16* __restrict__ A, const __bf16* __restrict__ Wob,
                     const float* __restrict__ bo, float* __restrict__ out)
{
    __shared__ __align__(16) __bf16 As[128 * 32];
    __shared__ __align__(16) __bf16 Bs[128 * 32];

    const int t    = threadIdx.x;
    const int w    = t >> 6, l = t & 63, quad = l >> 4, r16 = l & 15;
    const int wm   = w & 1, wn = w >> 1;
    const int m0   = blockIdx.y * 128;
    const int n0   = blockIdx.x * 128;

    floatx4 acc[4][4];
#pragma unroll
    for (int i = 0; i < 4; ++i)
#pragma unroll
        for (int j = 0; j < 4; ++j) acc[i][j] = (floatx4){0.f, 0.f, 0.f, 0.f};

    const int c0 = t, c1 = t + 256;
    const __bf16* Ag0 = A   + (size_t)(m0 + (c0 >> 2)) * 1024 + (c0 & 3) * 8;
    const __bf16* Ag1 = A   + (size_t)(m0 + (c1 >> 2)) * 1024 + (c1 & 3) * 8;
    const __bf16* Bg0 = Wob + (size_t)(n0 + (c0 >> 2)) * 1024 + (c0 & 3) * 8;
    const __bf16* Bg1 = Wob + (size_t)(n0 + (c1 >> 2)) * 1024 + (c1 & 3) * 8;
    unsigned int* lAs = (unsigned int*)As;
    unsigned int* lBs = (unsigned int*)Bs;

    for (int k0 = 0; k0 < 1024; k0 += 32) {
        __syncthreads();
        GLOAD_LDS16(Ag0 + k0, lAs + c0 * 4);
        GLOAD_LDS16(Ag1 + k0, lAs + c1 * 4);
        GLOAD_LDS16(Bg0 + k0, lBs + c0 * 4);
        GLOAD_LDS16(Bg1 + k0, lBs + c1 * 4);
        __syncthreads();

        bf16x8 af[4], bfm[4];
#pragma unroll
        for (int i = 0; i < 4; ++i)
            af[i] = *(const bf16x8*)&As[(wm * 64 + i * 16 + r16) * 32 + quad * 8];
#pragma unroll
        for (int j = 0; j < 4; ++j)
            bfm[j] = *(const bf16x8*)&Bs[(wn * 64 + j * 16 + r16) * 32 + quad * 8];
#pragma unroll
        for (int i = 0; i < 4; ++i)
#pragma unroll
            for (int j = 0; j < 4; ++j)
                acc[i][j] = MFMA16(af[i], bfm[j], acc[i][j]);
    }

#pragma unroll
    for (int i = 0; i < 4; ++i) {
        const int mg = m0 + wm * 64 + i * 16 + quad * 4;
#pragma unroll
        for (int j = 0; j < 4; ++j) {
            const int ng = n0 + wn * 64 + j * 16 + r16;
            const float bb = bo[ng];
#pragma unroll
            for (int r = 0; r < 4; ++r)
                out[(size_t)(mg + r) * 1024 + ng] = acc[i][j][r] + bb;
        }
    }
}

// ---------------------------------------------------------------------------
// Flash attention v3, causal. Q,K in [B,H,S,64]; V^T in [B,H,64,S] (all bf16).
// 128 q-rows/block, 4 waves x 32 rows (2 m-frags), k-tiles of 64.
// grid = (16, 64), heavy q-tiles first.
//
// Key structure (round-6 redesign, LDS-op-count driven):
//  * S^T = K·Q^T (operand-swapped MFMA): C-layout gives lane 4 CONSECUTIVE
//    k-values -> P stored with ds_write_b64 (4/mi, was 16 u16).
//  * Deferred softmax: no running max / alpha rescale (scores are O(1);
//    fminf(s,70) guards overflow). No per-tile cross-lane ops at all;
//    l = per-lane partials, reduced once at the end (2 shfls).
//  * V^T staged from global with b128 (transpose done by QKV epilogue).
//  * Next K/V^T tile prefetched into regs right after staging barrier.
// LDS rows stride 72 (144 B, 16B-aligned; all patterns ~natural bank floor).
// ---------------------------------------------------------------------------
__global__ __launch_bounds__(256)
void attn_kernel(const __bf16* __restrict__ Qg, const __bf16* __restrict__ Kg,
                 const __bf16* __restrict__ Vtg, __bf16* __restrict__ O)
{
    __shared__ __align__(16) __bf16 Ks[64 * 72];
    __shared__ __align__(16) __bf16 Vt[64 * 72];
    __shared__ __align__(16) __bf16 Ps[4][32 * 72];

    const int t    = threadIdx.x;
    const int w    = t >> 6, l = t & 63, quad = l >> 4, r16 = l & 15;
    const int qt   = (int)gridDim.x - 1 - (int)blockIdx.x;   // heavy first
    const int bh   = blockIdx.y;
    const int q0   = qt * 128;
    const size_t base = (size_t)bh * SEQ * DKH;
    __bf16* Pw = &Ps[w][0];

    // Q B-frags: B[kk=d][n=q], lane n=r16 -> q-row, kk = khalf*32+quad*8+e
    bf16x8 qf[2][2];
#pragma unroll
    for (int mi = 0; mi < 2; ++mi) {
        const int row = q0 + w * 32 + mi * 16 + r16;
        qf[mi][0] = *(const bf16x8*)&Qg[base + (size_t)row * 64 + quad * 8];
        qf[mi][1] = *(const bf16x8*)&Qg[base + (size_t)row * 64 + 32 + quad * 8];
    }

    floatx4 o[2][4];
#pragma unroll
    for (int mi = 0; mi < 2; ++mi)
#pragma unroll
        for (int j = 0; j < 4; ++j) o[mi][j] = (floatx4){0.f, 0.f, 0.f, 0.f};
    float lsum[2] = {0.f, 0.f};

    const int wrow0 = q0 + w * 32;
    const int nkt   = 2 * qt + 2;
    const int srow  = t >> 3;            // staging: 8 lanes per row (coalesced)
    const int sg    = (t & 7) * 8;

    bf16x8 pk[2], pv[2];
#pragma unroll
    for (int it = 0; it < 2; ++it) {     // prefetch kt=0
        const int row = it * 32 + srow;
        pk[it] = *(const bf16x8*)&Kg[base + (size_t)row * 64 + sg];
        pv[it] = *(const bf16x8*)&Vtg[base + (size_t)row * 2048 + sg];
    }

    for (int kt = 0; kt < nkt; ++kt) {
        __syncthreads();                 // prev tile readers done
#pragma unroll
        for (int it = 0; it < 2; ++it) {
            const int row = it * 32 + srow;
            *(bf16x8*)&Ks[row * 72 + sg] = pk[it];
            *(bf16x8*)&Vt[row * 72 + sg] = pv[it];
        }
        __syncthreads();                 // staging visible
        if (kt + 1 < nkt) {              // prefetch next (hidden under compute)
#pragma unroll
            for (int it = 0; it < 2; ++it) {
                const int row = it * 32 + srow;
                pk[it] = *(const bf16x8*)&Kg[base + (size_t)((kt + 1) * 64 + row) * 64 + sg];
                pv[it] = *(const bf16x8*)&Vtg[base + (size_t)row * 2048 + (kt + 1) * 64 + sg];
            }
        }

        const bool active = (kt * 64 <= wrow0 + 31);   // wave-uniform
        if (active) {
            // K A-frags: A[m=k_row][kk=d], lane m=r16 -> k_row=j*16+r16
            bf16x8 kf[4][2];
#pragma unroll
            for (int j = 0; j < 4; ++j) {
                kf[j][0] = *(const bf16x8*)&Ks[(j * 16 + r16) * 72 + quad * 8];
                kf[j][1] = *(const bf16x8*)&Ks[(j * 16 + r16) * 72 + 32 + quad * 8];
            }
#pragma unroll
            for (int mi = 0; mi < 2; ++mi) {
                const int rmin = wrow0 + mi * 16;
                if (kt * 64 > rmin + 15) continue;     // fully masked
                const int qg = rmin + r16;             // this lane's q-column
#pragma unroll
                for (int j = 0; j < 4; ++j) {
                    floatx4 z = (floatx4){0.f, 0.f, 0.f, 0.f};
                    z = MFMA16(kf[j][0], qf[mi][0], z);
                    z = MFMA16(kf[j][1], qf[mi][1], z);
                    // S^T C-layout: col=q (r16), row=k_local=j*16+quad*4+r
                    bf16x4 p4;
                    float ls = 0.f;
#pragma unroll
                    for (int r = 0; r < 4; ++r) {
                        const int kg = kt * 64 + j * 16 + quad * 4 + r;
                        float p = 0.f;
                        if (kg <= qg)
                            p = __expf(fminf(z[r] * 0.125f, 70.f));
                        ls += p;
                        p4[r] = (__bf16)p;
                    }
                    lsum[mi] += ls;
                    *(bf16x4*)&Pw[(mi * 16 + r16) * 72 + j * 16 + quad * 4] = p4;
                }
            }
        }
        __syncthreads();                 // P visible (cross-lane within wave)
        if (active) {
            // V B-frags: B[k=s][n=d], lane n=r16 -> d=jd*16+r16 (shared by mi)
            bf16x8 vf[4][2];
#pragma unroll
            for (int jd = 0; jd < 4; ++jd) {
                vf[jd][0] = *(const bf16x8*)&Vt[(jd * 16 + r16) * 72 + quad * 8];
                vf[jd][1] = *(const bf16x8*)&Vt[(jd * 16 + r16) * 72 + 32 + quad * 8];
            }
#pragma unroll
            for (int mi = 0; mi < 2; ++mi) {
                if (kt * 64 > wrow0 + mi * 16 + 15) continue;
                bf16x8 pf0 = *(const bf16x8*)&Pw[(mi * 16 + r16) * 72 + quad * 8];
                bf16x8 pf1 = *(const bf16x8*)&Pw[(mi * 16 + r16) * 72 + 32 + quad * 8];
#pragma unroll
                for (int jd = 0; jd < 4; ++jd) {
                    o[mi][jd] = MFMA16(pf0, vf[jd][0], o[mi][jd]);
                    o[mi][jd] = MFMA16(pf1, vf[jd][1], o[mi][jd]);
                }
            }
        }
    }

    // l: reduce per-lane partials across the 4 quad replicas (cols = r16)
    float lred[2];
#pragma unroll
    for (int mi = 0; mi < 2; ++mi) {
        float v = lsum[mi];
        v += __shfl_xor(v, 16, 64);
        v += __shfl_xor(v, 32, 64);
        lred[mi] = v;
    }

    // epilogue: O C-layout row q_loc=quad*4+r, col d=jd*16+r16; O /= l
    const int b = bh >> 4, h = bh & 15;
#pragma unroll
    for (int mi = 0; mi < 2; ++mi)
#pragma unroll
        for (int r = 0; r < 4; ++r) {
            const int qrow = wrow0 + mi * 16 + quad * 4 + r;
            const float lval = __shfl(lred[mi], quad * 4 + r, 64);
            const float inv = 1.f / lval;
#pragma unroll
            for (int jd = 0; jd < 4; ++jd) {
                const int d = jd * 16 + r16;
                O[((size_t)(b * SEQ + qrow) * D_MODEL) + h * 64 + d] =
                    (__bf16)(o[mi][jd][r] * inv);
            }
        }
}

// ---------------------------------------------------------------------------
extern "C" void kernel_launch(void* const* d_in, const int* in_sizes, int n_in,
                              void* d_out, int out_size, void* d_ws, size_t ws_size,
                              hipStream_t stream)
{
    (void)in_sizes; (void)n_in; (void)out_size; (void)ws_size;
    const float* x  = (const float*)d_in[0];
    const float* Wq = (const float*)d_in[1];
    const float* bq = (const float*)d_in[2];
    const float* Wk = (const float*)d_in[3];
    const float* bk = (const float*)d_in[4];
    const float* Wv = (const float*)d_in[5];
    const float* bv = (const float*)d_in[6];
    const float* Wo = (const float*)d_in[7];
    const float* bo = (const float*)d_in[8];
    float* out = (float*)d_out;

    const size_t n_elem = (size_t)MTOT * D_MODEL;       // 8388608
    const int    w_n    = D_MODEL * D_MODEL;            // 1048576
    // d_out doubles as scratch until the final GEMM:
    //   [0, n_elem) bf16          : Q  (dead after attn)
    //   [n_elem, n_elem+3M) bf16  : Wqb/Wkb/Wvb (dead after qkv)
    __bf16* Qb  = (__bf16*)d_out;
    __bf16* Wqb = (__bf16*)d_out + n_elem;
    __bf16* Wkb = Wqb + w_n;
    __bf16* Wvb = Wkb + w_n;
    // ws (48MB): K, V^T, attn-out; Wob overlays dead K after attn.
    __bf16* Kb  = (__bf16*)d_ws;
    __bf16* Vtb = Kb + n_elem;
    __bf16* Ab  = Vtb + n_elem;
    __bf16* Wob = Kb;

    cvt_kernel<<<w_n / 1024, 256, 0, stream>>>(Wq, Wqb, w_n);
    cvt_kernel<<<w_n / 1024, 256, 0, stream>>>(Wk, Wkb, w_n);
    cvt_kernel<<<w_n / 1024, 256, 0, stream>>>(Wv, Wvb, w_n);
    qkv_gemm_kernel<<<dim3(8, 64, 3), 256, 0, stream>>>(
        x, Wqb, bq, Wkb, bk, Wvb, bv, Qb, Kb, Vtb);
    attn_kernel<<<dim3(16, 64), 256, 0, stream>>>(Qb, Kb, Vtb, Ab);
    cvt_kernel<<<w_n / 1024, 256, 0, stream>>>(Wo, Wob, w_n);
    out_gemm_kernel<<<dim3(8, 64), 256, 0, stream>>>(Ab, Wob, bo, out);
}

// Round 7
// 356.840 us; speedup vs baseline: 1.8925x; 1.1252x over previous
//
#include <hip/hip_runtime.h>
#include <hip/hip_bf16.h>
#include <stdint.h>

// ---- problem constants ----
#define D_MODEL 1024
#define SEQ     2048
#define BATCH   4
#define NHEAD   16
#define DKH     64
#define MTOT    (BATCH * SEQ)      // 8192

typedef __bf16 bf16x8 __attribute__((ext_vector_type(8)));
typedef __bf16 bf16x4 __attribute__((ext_vector_type(4)));
typedef float  floatx4 __attribute__((ext_vector_type(4)));

#define GLOAD_LDS16(gp, lp)                                            \
    __builtin_amdgcn_global_load_lds(                                  \
        (const __attribute__((address_space(1))) unsigned int*)(gp),   \
        (__attribute__((address_space(3))) unsigned int*)(lp), 16, 0, 0)

#define MFMA16(a, b, c) __builtin_amdgcn_mfma_f32_16x16x32_bf16(a, b, c, 0, 0, 0)

// ---------------------------------------------------------------------------
// fp32 -> bf16: x (exact-size grid, no guard)
// ---------------------------------------------------------------------------
__global__ __launch_bounds__(256)
void cvt_x_kernel(const float* __restrict__ src, __bf16* __restrict__ dst)
{
    const int i = (blockIdx.x * 256 + threadIdx.x) * 4;
    floatx4 v = *(const floatx4*)(src + i);
    bf16x4 o;
    o[0] = (__bf16)v[0]; o[1] = (__bf16)v[1]; o[2] = (__bf16)v[2]; o[3] = (__bf16)v[3];
    *(bf16x4*)(dst + i) = o;
}

// fp32 -> bf16: Wq/Wk/Wv stacked into Wcat[3072,1024]. grid (1024, 3).
__global__ __launch_bounds__(256)
void cvt_w3_kernel(const float* __restrict__ Wq, const float* __restrict__ Wk,
                   const float* __restrict__ Wv, __bf16* __restrict__ Wcat)
{
    const int z = blockIdx.y;
    const float* src = (z == 0) ? Wq : ((z == 1) ? Wk : Wv);
    const int i = (blockIdx.x * 256 + threadIdx.x) * 4;
    floatx4 v = *(const floatx4*)(src + i);
    bf16x4 o;
    o[0] = (__bf16)v[0]; o[1] = (__bf16)v[1]; o[2] = (__bf16)v[2]; o[3] = (__bf16)v[3];
    *(bf16x4*)(Wcat + (size_t)z * (D_MODEL * D_MODEL) + i) = o;
}

// ---------------------------------------------------------------------------
// QKV GEMM v2 (pure m97): out[m,n] = sum_k xb[m,k]*Wcat[n,k] + bias, all bf16.
// M=8192, N=3072, K=1024; grid (24, 64). 128x128 tile, BK=32, 4 waves.
// Both operands staged via global_load_lds width=16 (slot c -> row c>>2,
// kgrp c&3; LDS byte = c*16 matches wave-uniform-base + lane*16).
// z = n0>>10 (block-uniform): 0->Q [b,h,s,d], 1->K [b,h,s,d], 2->V^T [b,h,d,s].
// ---------------------------------------------------------------------------
__global__ __launch_bounds__(256)
void qkv_gemm_kernel(const __bf16* __restrict__ xb, const __bf16* __restrict__ Wcat,
                     const float* __restrict__ bq, const float* __restrict__ bk,
                     const float* __restrict__ bv,
                     __bf16* __restrict__ Q, __bf16* __restrict__ K,
                     __bf16* __restrict__ Vt)
{
    __shared__ __align__(16) __bf16 As[128 * 32];
    __shared__ __align__(16) __bf16 Bs[128 * 32];

    const int t    = threadIdx.x;
    const int w    = t >> 6, l = t & 63, quad = l >> 4, r16 = l & 15;
    const int wm   = w & 1, wn = w >> 1;
    const int m0   = blockIdx.y * 128;
    const int n0   = blockIdx.x * 128;
    const int z    = n0 >> 10;                        // block-uniform
    const float* bias = (z == 0) ? bq : ((z == 1) ? bk : bv);
    __bf16* outQK     = (z == 0) ? Q  : K;

    floatx4 acc[4][4];
#pragma unroll
    for (int i = 0; i < 4; ++i)
#pragma unroll
        for (int j = 0; j < 4; ++j) acc[i][j] = (floatx4){0.f, 0.f, 0.f, 0.f};

    const int c0 = t, c1 = t + 256;
    const __bf16* Ag0 = xb   + (size_t)(m0 + (c0 >> 2)) * 1024 + (c0 & 3) * 8;
    const __bf16* Ag1 = xb   + (size_t)(m0 + (c1 >> 2)) * 1024 + (c1 & 3) * 8;
    const __bf16* Bg0 = Wcat + (size_t)(n0 + (c0 >> 2)) * 1024 + (c0 & 3) * 8;
    const __bf16* Bg1 = Wcat + (size_t)(n0 + (c1 >> 2)) * 1024 + (c1 & 3) * 8;
    unsigned int* lAs = (unsigned int*)As;
    unsigned int* lBs = (unsigned int*)Bs;

    for (int k0 = 0; k0 < 1024; k0 += 32) {
        __syncthreads();
        GLOAD_LDS16(Ag0 + k0, lAs + c0 * 4);
        GLOAD_LDS16(Ag1 + k0, lAs + c1 * 4);
        GLOAD_LDS16(Bg0 + k0, lBs + c0 * 4);
        GLOAD_LDS16(Bg1 + k0, lBs + c1 * 4);
        __syncthreads();

        bf16x8 af[4], bfm[4];
#pragma unroll
        for (int i = 0; i < 4; ++i)
            af[i] = *(const bf16x8*)&As[(wm * 64 + i * 16 + r16) * 32 + quad * 8];
#pragma unroll
        for (int j = 0; j < 4; ++j)
            bfm[j] = *(const bf16x8*)&Bs[(wn * 64 + j * 16 + r16) * 32 + quad * 8];
#pragma unroll
        for (int i = 0; i < 4; ++i)
#pragma unroll
            for (int j = 0; j < 4; ++j)
                acc[i][j] = MFMA16(af[i], bfm[j], acc[i][j]);
    }

    // epilogue: C/D row = quad*4 + r, col = r16
#pragma unroll
    for (int i = 0; i < 4; ++i) {
        const int mg = m0 + wm * 64 + i * 16 + quad * 4;
#pragma unroll
        for (int j = 0; j < 4; ++j) {
            const int ng = n0 + wn * 64 + j * 16 + r16;
            const int f = ng & 1023, h = f >> 6, d = f & 63;
            const float bb = bias[f];
#pragma unroll
            for (int r = 0; r < 4; ++r) {
                const int m = mg + r;
                const int b = m >> 11, s = m & 2047;
                const float v = acc[i][j][r] + bb;
                if (z == 2)   // V^T: [b,h,d,s]
                    Vt[((size_t)((b * 16 + h) * 64 + d) << 11) + s] = (__bf16)v;
                else          // Q/K: [b,h,s,d]
                    outQK[((size_t)(b * 16 + h) << 17) + ((size_t)s << 6) + d] =
                        (__bf16)v;
            }
        }
    }
}

// ---------------------------------------------------------------------------
// Output GEMM (m97 structure, unchanged)
// ---------------------------------------------------------------------------
__global__ __launch_bounds__(256)
void out_gemm_kernel(const __bf16* __restrict__ A, const __bf16* __restrict__ Wob,
                     const float* __restrict__ bo, float* __restrict__ out)
{
    __shared__ __align__(16) __bf16 As[128 * 32];
    __shared__ __align__(16) __bf16 Bs[128 * 32];

    const int t    = threadIdx.x;
    const int w    = t >> 6, l = t & 63, quad = l >> 4, r16 = l & 15;
    const int wm   = w & 1, wn = w >> 1;
    const int m0   = blockIdx.y * 128;
    const int n0   = blockIdx.x * 128;

    floatx4 acc[4][4];
#pragma unroll
    for (int i = 0; i < 4; ++i)
#pragma unroll
        for (int j = 0; j < 4; ++j) acc[i][j] = (floatx4){0.f, 0.f, 0.f, 0.f};

    const int c0 = t, c1 = t + 256;
    const __bf16* Ag0 = A   + (size_t)(m0 + (c0 >> 2)) * 1024 + (c0 & 3) * 8;
    const __bf16* Ag1 = A   + (size_t)(m0 + (c1 >> 2)) * 1024 + (c1 & 3) * 8;
    const __bf16* Bg0 = Wob + (size_t)(n0 + (c0 >> 2)) * 1024 + (c0 & 3) * 8;
    const __bf16* Bg1 = Wob + (size_t)(n0 + (c1 >> 2)) * 1024 + (c1 & 3) * 8;
    unsigned int* lAs = (unsigned int*)As;
    unsigned int* lBs = (unsigned int*)Bs;

    for (int k0 = 0; k0 < 1024; k0 += 32) {
        __syncthreads();
        GLOAD_LDS16(Ag0 + k0, lAs + c0 * 4);
        GLOAD_LDS16(Ag1 + k0, lAs + c1 * 4);
        GLOAD_LDS16(Bg0 + k0, lBs + c0 * 4);
        GLOAD_LDS16(Bg1 + k0, lBs + c1 * 4);
        __syncthreads();

        bf16x8 af[4], bfm[4];
#pragma unroll
        for (int i = 0; i < 4; ++i)
            af[i] = *(const bf16x8*)&As[(wm * 64 + i * 16 + r16) * 32 + quad * 8];
#pragma unroll
        for (int j = 0; j < 4; ++j)
            bfm[j] = *(const bf16x8*)&Bs[(wn * 64 + j * 16 + r16) * 32 + quad * 8];
#pragma unroll
        for (int i = 0; i < 4; ++i)
#pragma unroll
            for (int j = 0; j < 4; ++j)
                acc[i][j] = MFMA16(af[i], bfm[j], acc[i][j]);
    }

#pragma unroll
    for (int i = 0; i < 4; ++i) {
        const int mg = m0 + wm * 64 + i * 16 + quad * 4;
#pragma unroll
        for (int j = 0; j < 4; ++j) {
            const int ng = n0 + wn * 64 + j * 16 + r16;
            const float bb = bo[ng];
#pragma unroll
            for (int r = 0; r < 4; ++r)
                out[(size_t)(mg + r) * 1024 + ng] = acc[i][j][r] + bb;
        }
    }
}

// ---------------------------------------------------------------------------
// Flash attention v3 (round-6 structure, unchanged — it won).
// Q,K in [B,H,S,64]; V^T in [B,H,64,S]; out [B,S,H*64] bf16.
// S^T = K·Q^T (operand swap) -> P stores are b64; deferred softmax (no
// running max; fminf(s,70) guard); reg prefetch of next K/V^T tile.
// ---------------------------------------------------------------------------
__global__ __launch_bounds__(256)
void attn_kernel(const __bf16* __restrict__ Qg, const __bf16* __restrict__ Kg,
                 const __bf16* __restrict__ Vtg, __bf16* __restrict__ O)
{
    __shared__ __align__(16) __bf16 Ks[64 * 72];
    __shared__ __align__(16) __bf16 Vt[64 * 72];
    __shared__ __align__(16) __bf16 Ps[4][32 * 72];

    const int t    = threadIdx.x;
    const int w    = t >> 6, l = t & 63, quad = l >> 4, r16 = l & 15;
    const int qt   = (int)gridDim.x - 1 - (int)blockIdx.x;   // heavy first
    const int bh   = blockIdx.y;
    const int q0   = qt * 128;
    const size_t base = (size_t)bh * SEQ * DKH;
    __bf16* Pw = &Ps[w][0];

    bf16x8 qf[2][2];
#pragma unroll
    for (int mi = 0; mi < 2; ++mi) {
        const int row = q0 + w * 32 + mi * 16 + r16;
        qf[mi][0] = *(const bf16x8*)&Qg[base + (size_t)row * 64 + quad * 8];
        qf[mi][1] = *(const bf16x8*)&Qg[base + (size_t)row * 64 + 32 + quad * 8];
    }

    floatx4 o[2][4];
#pragma unroll
    for (int mi = 0; mi < 2; ++mi)
#pragma unroll
        for (int j = 0; j < 4; ++j) o[mi][j] = (floatx4){0.f, 0.f, 0.f, 0.f};
    float lsum[2] = {0.f, 0.f};

    const int wrow0 = q0 + w * 32;
    const int nkt   = 2 * qt + 2;
    const int srow  = t >> 3;
    const int sg    = (t & 7) * 8;

    bf16x8 pk[2], pv[2];
#pragma unroll
    for (int it = 0; it < 2; ++it) {
        const int row = it * 32 + srow;
        pk[it] = *(const bf16x8*)&Kg[base + (size_t)row * 64 + sg];
        pv[it] = *(const bf16x8*)&Vtg[base + (size_t)row * 2048 + sg];
    }

    for (int kt = 0; kt < nkt; ++kt) {
        __syncthreads();
#pragma unroll
        for (int it = 0; it < 2; ++it) {
            const int row = it * 32 + srow;
            *(bf16x8*)&Ks[row * 72 + sg] = pk[it];
            *(bf16x8*)&Vt[row * 72 + sg] = pv[it];
        }
        __syncthreads();
        if (kt + 1 < nkt) {
#pragma unroll
            for (int it = 0; it < 2; ++it) {
                const int row = it * 32 + srow;
                pk[it] = *(const bf16x8*)&Kg[base + (size_t)((kt + 1) * 64 + row) * 64 + sg];
                pv[it] = *(const bf16x8*)&Vtg[base + (size_t)row * 2048 + (kt + 1) * 64 + sg];
            }
        }

        const bool active = (kt * 64 <= wrow0 + 31);
        if (active) {
            bf16x8 kf[4][2];
#pragma unroll
            for (int j = 0; j < 4; ++j) {
                kf[j][0] = *(const bf16x8*)&Ks[(j * 16 + r16) * 72 + quad * 8];
                kf[j][1] = *(const bf16x8*)&Ks[(j * 16 + r16) * 72 + 32 + quad * 8];
            }
#pragma unroll
            for (int mi = 0; mi < 2; ++mi) {
                const int rmin = wrow0 + mi * 16;
                if (kt * 64 > rmin + 15) continue;
                const int qg = rmin + r16;
#pragma unroll
                for (int j = 0; j < 4; ++j) {
                    floatx4 z = (floatx4){0.f, 0.f, 0.f, 0.f};
                    z = MFMA16(kf[j][0], qf[mi][0], z);
                    z = MFMA16(kf[j][1], qf[mi][1], z);
                    bf16x4 p4;
                    float ls = 0.f;
#pragma unroll
                    for (int r = 0; r < 4; ++r) {
                        const int kg = kt * 64 + j * 16 + quad * 4 + r;
                        float p = 0.f;
                        if (kg <= qg)
                            p = __expf(fminf(z[r] * 0.125f, 70.f));
                        ls += p;
                        p4[r] = (__bf16)p;
                    }
                    lsum[mi] += ls;
                    *(bf16x4*)&Pw[(mi * 16 + r16) * 72 + j * 16 + quad * 4] = p4;
                }
            }
        }
        __syncthreads();
        if (active) {
            bf16x8 vf[4][2];
#pragma unroll
            for (int jd = 0; jd < 4; ++jd) {
                vf[jd][0] = *(const bf16x8*)&Vt[(jd * 16 + r16) * 72 + quad * 8];
                vf[jd][1] = *(const bf16x8*)&Vt[(jd * 16 + r16) * 72 + 32 + quad * 8];
            }
#pragma unroll
            for (int mi = 0; mi < 2; ++mi) {
                if (kt * 64 > wrow0 + mi * 16 + 15) continue;
                bf16x8 pf0 = *(const bf16x8*)&Pw[(mi * 16 + r16) * 72 + quad * 8];
                bf16x8 pf1 = *(const bf16x8*)&Pw[(mi * 16 + r16) * 72 + 32 + quad * 8];
#pragma unroll
                for (int jd = 0; jd < 4; ++jd) {
                    o[mi][jd] = MFMA16(pf0, vf[jd][0], o[mi][jd]);
                    o[mi][jd] = MFMA16(pf1, vf[jd][1], o[mi][jd]);
                }
            }
        }
    }

    float lred[2];
#pragma unroll
    for (int mi = 0; mi < 2; ++mi) {
        float v = lsum[mi];
        v += __shfl_xor(v, 16, 64);
        v += __shfl_xor(v, 32, 64);
        lred[mi] = v;
    }

    const int b = bh >> 4, h = bh & 15;
#pragma unroll
    for (int mi = 0; mi < 2; ++mi)
#pragma unroll
        for (int r = 0; r < 4; ++r) {
            const int qrow = wrow0 + mi * 16 + quad * 4 + r;
            const float lval = __shfl(lred[mi], quad * 4 + r, 64);
            const float inv = 1.f / lval;
#pragma unroll
            for (int jd = 0; jd < 4; ++jd) {
                const int d = jd * 16 + r16;
                O[((size_t)(b * SEQ + qrow) * D_MODEL) + h * 64 + d] =
                    (__bf16)(o[mi][jd][r] * inv);
            }
        }
}

// ---------------------------------------------------------------------------
extern "C" void kernel_launch(void* const* d_in, const int* in_sizes, int n_in,
                              void* d_out, int out_size, void* d_ws, size_t ws_size,
                              hipStream_t stream)
{
    (void)in_sizes; (void)n_in; (void)out_size; (void)ws_size;
    const float* x  = (const float*)d_in[0];
    const float* Wq = (const float*)d_in[1];
    const float* bq = (const float*)d_in[2];
    const float* Wk = (const float*)d_in[3];
    const float* bk = (const float*)d_in[4];
    const float* Wv = (const float*)d_in[5];
    const float* bv = (const float*)d_in[6];
    const float* Wo = (const float*)d_in[7];
    const float* bo = (const float*)d_in[8];
    float* out = (float*)d_out;

    const size_t n_elem = (size_t)MTOT * D_MODEL;       // 8388608
    const int    w_n    = D_MODEL * D_MODEL;            // 1048576
    // d_out (33.55MB) as scratch until final GEMM: [Qb bf16][xb bf16] (exact).
    __bf16* Qb  = (__bf16*)d_out;
    __bf16* xb  = Qb + n_elem;
    // ws (48MB): [K][V^T][Ab]. Wcat (6.3MB) overlays dead-until-attn Ab;
    // Wob (2MB) overlays dead-after-attn K.
    __bf16* Kb   = (__bf16*)d_ws;
    __bf16* Vtb  = Kb + n_elem;
    __bf16* Ab   = Vtb + n_elem;
    __bf16* Wcat = Ab;             // dead once attn starts writing Ab? No:
    // Wcat is consumed by qkv_gemm BEFORE attn runs; attn then overwrites. OK.
    __bf16* Wob  = Kb;

    cvt_x_kernel<<<MTOT * D_MODEL / 1024, 256, 0, stream>>>(x, xb);
    cvt_w3_kernel<<<dim3(w_n / 1024, 3), 256, 0, stream>>>(Wq, Wk, Wv, Wcat);
    qkv_gemm_kernel<<<dim3(24, 64), 256, 0, stream>>>(xb, Wcat, bq, bk, bv,
                                                      Qb, Kb, Vtb);
    attn_kernel<<<dim3(16, 64), 256, 0, stream>>>(Qb, Kb, Vtb, Ab);
    cvt_x_kernel<<<w_n / 1024, 256, 0, stream>>>(Wo, Wob);
    out_gemm_kernel<<<dim3(8, 64), 256, 0, stream>>>(Ab, Wob, bo, out);
}

// Round 8
// 320.323 us; speedup vs baseline: 2.1083x; 1.1140x over previous
//
#include <hip/hip_runtime.h>
#include <hip/hip_bf16.h>
#include <stdint.h>

// ---- problem constants ----
#define D_MODEL 1024
#define SEQ     2048
#define BATCH   4
#define NHEAD   16
#define DKH     64
#define MTOT    (BATCH * SEQ)      // 8192

typedef __bf16 bf16x8 __attribute__((ext_vector_type(8)));
typedef __bf16 bf16x4 __attribute__((ext_vector_type(4)));
typedef float  floatx4 __attribute__((ext_vector_type(4)));

#define GLOAD_LDS16(gp, lp)                                            \
    __builtin_amdgcn_global_load_lds(                                  \
        (const __attribute__((address_space(1))) unsigned int*)(gp),   \
        (__attribute__((address_space(3))) unsigned int*)(lp), 16, 0, 0)

#define MFMA16(a, b, c) __builtin_amdgcn_mfma_f32_16x16x32_bf16(a, b, c, 0, 0, 0)

// ---------------------------------------------------------------------------
// fp32 -> bf16: x (exact-size grid, no guard)
// ---------------------------------------------------------------------------
__global__ __launch_bounds__(256)
void cvt_x_kernel(const float* __restrict__ src, __bf16* __restrict__ dst)
{
    const int i = (blockIdx.x * 256 + threadIdx.x) * 4;
    floatx4 v = *(const floatx4*)(src + i);
    bf16x4 o;
    o[0] = (__bf16)v[0]; o[1] = (__bf16)v[1]; o[2] = (__bf16)v[2]; o[3] = (__bf16)v[3];
    *(bf16x4*)(dst + i) = o;
}

// fp32 -> bf16: Wq/Wk/Wv stacked into Wcat[3072,1024]. grid (1024, 3).
__global__ __launch_bounds__(256)
void cvt_w3_kernel(const float* __restrict__ Wq, const float* __restrict__ Wk,
                   const float* __restrict__ Wv, __bf16* __restrict__ Wcat)
{
    const int z = blockIdx.y;
    const float* src = (z == 0) ? Wq : ((z == 1) ? Wk : Wv);
    const int i = (blockIdx.x * 256 + threadIdx.x) * 4;
    floatx4 v = *(const floatx4*)(src + i);
    bf16x4 o;
    o[0] = (__bf16)v[0]; o[1] = (__bf16)v[1]; o[2] = (__bf16)v[2]; o[3] = (__bf16)v[3];
    *(bf16x4*)(Wcat + (size_t)z * (D_MODEL * D_MODEL) + i) = o;
}

// ---------------------------------------------------------------------------
// QKV GEMM (pure m97): out[m,n] = sum_k xb[m,k]*Wcat[n,k] + bias, all bf16.
// M=8192, N=3072, K=1024; grid (24, 64). 128x128 tile, BK=32, 4 waves.
// z = n0>>10: 0->Q [b,h,s,d] (PRE-SCALED by 1/8), 1->K, 2->V^T [b,h,d,s].
// ---------------------------------------------------------------------------
__global__ __launch_bounds__(256)
void qkv_gemm_kernel(const __bf16* __restrict__ xb, const __bf16* __restrict__ Wcat,
                     const float* __restrict__ bq, const float* __restrict__ bk,
                     const float* __restrict__ bv,
                     __bf16* __restrict__ Q, __bf16* __restrict__ K,
                     __bf16* __restrict__ Vt)
{
    __shared__ __align__(16) __bf16 As[128 * 32];
    __shared__ __align__(16) __bf16 Bs[128 * 32];

    const int t    = threadIdx.x;
    const int w    = t >> 6, l = t & 63, quad = l >> 4, r16 = l & 15;
    const int wm   = w & 1, wn = w >> 1;
    const int m0   = blockIdx.y * 128;
    const int n0   = blockIdx.x * 128;
    const int z    = n0 >> 10;                        // block-uniform
    const float* bias = (z == 0) ? bq : ((z == 1) ? bk : bv);
    __bf16* outQK     = (z == 0) ? Q  : K;
    const float scale = (z == 0) ? 0.125f : 1.0f;     // fold 1/sqrt(64) into Q

    floatx4 acc[4][4];
#pragma unroll
    for (int i = 0; i < 4; ++i)
#pragma unroll
        for (int j = 0; j < 4; ++j) acc[i][j] = (floatx4){0.f, 0.f, 0.f, 0.f};

    const int c0 = t, c1 = t + 256;
    const __bf16* Ag0 = xb   + (size_t)(m0 + (c0 >> 2)) * 1024 + (c0 & 3) * 8;
    const __bf16* Ag1 = xb   + (size_t)(m0 + (c1 >> 2)) * 1024 + (c1 & 3) * 8;
    const __bf16* Bg0 = Wcat + (size_t)(n0 + (c0 >> 2)) * 1024 + (c0 & 3) * 8;
    const __bf16* Bg1 = Wcat + (size_t)(n0 + (c1 >> 2)) * 1024 + (c1 & 3) * 8;
    unsigned int* lAs = (unsigned int*)As;
    unsigned int* lBs = (unsigned int*)Bs;

    for (int k0 = 0; k0 < 1024; k0 += 32) {
        __syncthreads();
        GLOAD_LDS16(Ag0 + k0, lAs + c0 * 4);
        GLOAD_LDS16(Ag1 + k0, lAs + c1 * 4);
        GLOAD_LDS16(Bg0 + k0, lBs + c0 * 4);
        GLOAD_LDS16(Bg1 + k0, lBs + c1 * 4);
        __syncthreads();

        bf16x8 af[4], bfm[4];
#pragma unroll
        for (int i = 0; i < 4; ++i)
            af[i] = *(const bf16x8*)&As[(wm * 64 + i * 16 + r16) * 32 + quad * 8];
#pragma unroll
        for (int j = 0; j < 4; ++j)
            bfm[j] = *(const bf16x8*)&Bs[(wn * 64 + j * 16 + r16) * 32 + quad * 8];
#pragma unroll
        for (int i = 0; i < 4; ++i)
#pragma unroll
            for (int j = 0; j < 4; ++j)
                acc[i][j] = MFMA16(af[i], bfm[j], acc[i][j]);
    }

    // epilogue: C/D row = quad*4 + r, col = r16
#pragma unroll
    for (int i = 0; i < 4; ++i) {
        const int mg = m0 + wm * 64 + i * 16 + quad * 4;
#pragma unroll
        for (int j = 0; j < 4; ++j) {
            const int ng = n0 + wn * 64 + j * 16 + r16;
            const int f = ng & 1023, h = f >> 6, d = f & 63;
            const float bb = bias[f];
#pragma unroll
            for (int r = 0; r < 4; ++r) {
                const int m = mg + r;
                const int b = m >> 11, s = m & 2047;
                const float v = (acc[i][j][r] + bb) * scale;
                if (z == 2)   // V^T: [b,h,d,s]
                    Vt[((size_t)((b * 16 + h) * 64 + d) << 11) + s] = (__bf16)v;
                else          // Q/K: [b,h,s,d]
                    outQK[((size_t)(b * 16 + h) << 17) + ((size_t)s << 6) + d] =
                        (__bf16)v;
            }
        }
    }
}

// ---------------------------------------------------------------------------
// Output GEMM (m97 structure, unchanged)
// ---------------------------------------------------------------------------
__global__ __launch_bounds__(256)
void out_gemm_kernel(const __bf16* __restrict__ A, const __bf16* __restrict__ Wob,
                     const float* __restrict__ bo, float* __restrict__ out)
{
    __shared__ __align__(16) __bf16 As[128 * 32];
    __shared__ __align__(16) __bf16 Bs[128 * 32];

    const int t    = threadIdx.x;
    const int w    = t >> 6, l = t & 63, quad = l >> 4, r16 = l & 15;
    const int wm   = w & 1, wn = w >> 1;
    const int m0   = blockIdx.y * 128;
    const int n0   = blockIdx.x * 128;

    floatx4 acc[4][4];
#pragma unroll
    for (int i = 0; i < 4; ++i)
#pragma unroll
        for (int j = 0; j < 4; ++j) acc[i][j] = (floatx4){0.f, 0.f, 0.f, 0.f};

    const int c0 = t, c1 = t + 256;
    const __bf16* Ag0 = A   + (size_t)(m0 + (c0 >> 2)) * 1024 + (c0 & 3) * 8;
    const __bf16* Ag1 = A   + (size_t)(m0 + (c1 >> 2)) * 1024 + (c1 & 3) * 8;
    const __bf16* Bg0 = Wob + (size_t)(n0 + (c0 >> 2)) * 1024 + (c0 & 3) * 8;
    const __bf16* Bg1 = Wob + (size_t)(n0 + (c1 >> 2)) * 1024 + (c1 & 3) * 8;
    unsigned int* lAs = (unsigned int*)As;
    unsigned int* lBs = (unsigned int*)Bs;

    for (int k0 = 0; k0 < 1024; k0 += 32) {
        __syncthreads();
        GLOAD_LDS16(Ag0 + k0, lAs + c0 * 4);
        GLOAD_LDS16(Ag1 + k0, lAs + c1 * 4);
        GLOAD_LDS16(Bg0 + k0, lBs + c0 * 4);
        GLOAD_LDS16(Bg1 + k0, lBs + c1 * 4);
        __syncthreads();

        bf16x8 af[4], bfm[4];
#pragma unroll
        for (int i = 0; i < 4; ++i)
            af[i] = *(const bf16x8*)&As[(wm * 64 + i * 16 + r16) * 32 + quad * 8];
#pragma unroll
        for (int j = 0; j < 4; ++j)
            bfm[j] = *(const bf16x8*)&Bs[(wn * 64 + j * 16 + r16) * 32 + quad * 8];
#pragma unroll
        for (int i = 0; i < 4; ++i)
#pragma unroll
            for (int j = 0; j < 4; ++j)
                acc[i][j] = MFMA16(af[i], bfm[j], acc[i][j]);
    }

#pragma unroll
    for (int i = 0; i < 4; ++i) {
        const int mg = m0 + wm * 64 + i * 16 + quad * 4;
#pragma unroll
        for (int j = 0; j < 4; ++j) {
            const int ng = n0 + wn * 64 + j * 16 + r16;
            const float bb = bo[ng];
#pragma unroll
            for (int r = 0; r < 4; ++r)
                out[(size_t)(mg + r) * 1024 + ng] = acc[i][j][r] + bb;
        }
    }
}

// ---------------------------------------------------------------------------
// Flash attention v4. Q (pre-scaled by 1/8), K in [B,H,S,64]; V^T [B,H,64,S].
// Round-8 changes:
//  * Work-balancing qt swizzle: co-resident blocks (linear ids 256 apart =
//    same x, y+16k) alternate qt <-> 15-qt, so every CU gets exactly 68
//    k-tiles (was 8..128 -> tail-bound at occupancy 11%).
//  * P round-trip: wave-private region, __syncthreads replaced by wave-local
//    s_waitcnt lgkmcnt(0) + compiler fence (2 barriers/tile instead of 3).
//  * Score scale folded into Q upstream.
// ---------------------------------------------------------------------------
__global__ __launch_bounds__(256)
void attn_kernel(const __bf16* __restrict__ Qg, const __bf16* __restrict__ Kg,
                 const __bf16* __restrict__ Vtg, __bf16* __restrict__ O)
{
    __shared__ __align__(16) __bf16 Ks[64 * 72];
    __shared__ __align__(16) __bf16 Vt[64 * 72];
    __shared__ __align__(16) __bf16 Ps[4][32 * 72];

    const int t    = threadIdx.x;
    const int w    = t >> 6, l = t & 63, quad = l >> 4, r16 = l & 15;
    const int bh   = blockIdx.y;
    // balance: XCD round-robin puts linear ids {n, n+256, n+512, n+768} on one
    // CU -> same blockIdx.x, blockIdx.y differing by 16. Alternate qt/15-qt.
    const int qt   = ((blockIdx.y >> 4) & 1) ? (15 - (int)blockIdx.x)
                                             : (int)blockIdx.x;
    const int q0   = qt * 128;
    const size_t base = (size_t)bh * SEQ * DKH;
    __bf16* Pw = &Ps[w][0];

    bf16x8 qf[2][2];
#pragma unroll
    for (int mi = 0; mi < 2; ++mi) {
        const int row = q0 + w * 32 + mi * 16 + r16;
        qf[mi][0] = *(const bf16x8*)&Qg[base + (size_t)row * 64 + quad * 8];
        qf[mi][1] = *(const bf16x8*)&Qg[base + (size_t)row * 64 + 32 + quad * 8];
    }

    floatx4 o[2][4];
#pragma unroll
    for (int mi = 0; mi < 2; ++mi)
#pragma unroll
        for (int j = 0; j < 4; ++j) o[mi][j] = (floatx4){0.f, 0.f, 0.f, 0.f};
    float lsum[2] = {0.f, 0.f};

    const int wrow0 = q0 + w * 32;
    const int nkt   = 2 * qt + 2;
    const int srow  = t >> 3;
    const int sg    = (t & 7) * 8;

    bf16x8 pk[2], pv[2];
#pragma unroll
    for (int it = 0; it < 2; ++it) {
        const int row = it * 32 + srow;
        pk[it] = *(const bf16x8*)&Kg[base + (size_t)row * 64 + sg];
        pv[it] = *(const bf16x8*)&Vtg[base + (size_t)row * 2048 + sg];
    }

    for (int kt = 0; kt < nkt; ++kt) {
        __syncthreads();                 // prev tile readers done
#pragma unroll
        for (int it = 0; it < 2; ++it) {
            const int row = it * 32 + srow;
            *(bf16x8*)&Ks[row * 72 + sg] = pk[it];
            *(bf16x8*)&Vt[row * 72 + sg] = pv[it];
        }
        __syncthreads();                 // staging visible
        if (kt + 1 < nkt) {
#pragma unroll
            for (int it = 0; it < 2; ++it) {
                const int row = it * 32 + srow;
                pk[it] = *(const bf16x8*)&Kg[base + (size_t)((kt + 1) * 64 + row) * 64 + sg];
                pv[it] = *(const bf16x8*)&Vtg[base + (size_t)row * 2048 + (kt + 1) * 64 + sg];
            }
        }

        const bool active = (kt * 64 <= wrow0 + 31);   // wave-uniform
        if (active) {
            bf16x8 kf[4][2];
#pragma unroll
            for (int j = 0; j < 4; ++j) {
                kf[j][0] = *(const bf16x8*)&Ks[(j * 16 + r16) * 72 + quad * 8];
                kf[j][1] = *(const bf16x8*)&Ks[(j * 16 + r16) * 72 + 32 + quad * 8];
            }
#pragma unroll
            for (int mi = 0; mi < 2; ++mi) {
                const int rmin = wrow0 + mi * 16;
                if (kt * 64 > rmin + 15) continue;
                const int qg = rmin + r16;
#pragma unroll
                for (int j = 0; j < 4; ++j) {
                    floatx4 z = (floatx4){0.f, 0.f, 0.f, 0.f};
                    z = MFMA16(kf[j][0], qf[mi][0], z);
                    z = MFMA16(kf[j][1], qf[mi][1], z);
                    bf16x4 p4;
                    float ls = 0.f;
#pragma unroll
                    for (int r = 0; r < 4; ++r) {
                        const int kg = kt * 64 + j * 16 + quad * 4 + r;
                        float p = 0.f;
                        if (kg <= qg)
                            p = __expf(fminf(z[r], 70.f));
                        ls += p;
                        p4[r] = (__bf16)p;
                    }
                    lsum[mi] += ls;
                    *(bf16x4*)&Pw[(mi * 16 + r16) * 72 + j * 16 + quad * 4] = p4;
                }
            }
            // wave-private P region: wave-local drain is sufficient (DS ops
            // retire before subsequent reads issue); fence stops reordering.
            __asm__ __volatile__("s_waitcnt lgkmcnt(0)" ::: "memory");

            bf16x8 vf[4][2];
#pragma unroll
            for (int jd = 0; jd < 4; ++jd) {
                vf[jd][0] = *(const bf16x8*)&Vt[(jd * 16 + r16) * 72 + quad * 8];
                vf[jd][1] = *(const bf16x8*)&Vt[(jd * 16 + r16) * 72 + 32 + quad * 8];
            }
#pragma unroll
            for (int mi = 0; mi < 2; ++mi) {
                if (kt * 64 > wrow0 + mi * 16 + 15) continue;
                bf16x8 pf0 = *(const bf16x8*)&Pw[(mi * 16 + r16) * 72 + quad * 8];
                bf16x8 pf1 = *(const bf16x8*)&Pw[(mi * 16 + r16) * 72 + 32 + quad * 8];
#pragma unroll
                for (int jd = 0; jd < 4; ++jd) {
                    o[mi][jd] = MFMA16(pf0, vf[jd][0], o[mi][jd]);
                    o[mi][jd] = MFMA16(pf1, vf[jd][1], o[mi][jd]);
                }
            }
        }
    }

    float lred[2];
#pragma unroll
    for (int mi = 0; mi < 2; ++mi) {
        float v = lsum[mi];
        v += __shfl_xor(v, 16, 64);
        v += __shfl_xor(v, 32, 64);
        lred[mi] = v;
    }

    const int b = bh >> 4, h = bh & 15;
#pragma unroll
    for (int mi = 0; mi < 2; ++mi)
#pragma unroll
        for (int r = 0; r < 4; ++r) {
            const int qrow = wrow0 + mi * 16 + quad * 4 + r;
            const float lval = __shfl(lred[mi], quad * 4 + r, 64);
            const float inv = 1.f / lval;
#pragma unroll
            for (int jd = 0; jd < 4; ++jd) {
                const int d = jd * 16 + r16;
                O[((size_t)(b * SEQ + qrow) * D_MODEL) + h * 64 + d] =
                    (__bf16)(o[mi][jd][r] * inv);
            }
        }
}

// ---------------------------------------------------------------------------
extern "C" void kernel_launch(void* const* d_in, const int* in_sizes, int n_in,
                              void* d_out, int out_size, void* d_ws, size_t ws_size,
                              hipStream_t stream)
{
    (void)in_sizes; (void)n_in; (void)out_size; (void)ws_size;
    const float* x  = (const float*)d_in[0];
    const float* Wq = (const float*)d_in[1];
    const float* bq = (const float*)d_in[2];
    const float* Wk = (const float*)d_in[3];
    const float* bk = (const float*)d_in[4];
    const float* Wv = (const float*)d_in[5];
    const float* bv = (const float*)d_in[6];
    const float* Wo = (const float*)d_in[7];
    const float* bo = (const float*)d_in[8];
    float* out = (float*)d_out;

    const size_t n_elem = (size_t)MTOT * D_MODEL;       // 8388608
    const int    w_n    = D_MODEL * D_MODEL;            // 1048576
    // d_out (33.55MB) as scratch until final GEMM: [Qb bf16][xb bf16].
    __bf16* Qb  = (__bf16*)d_out;
    __bf16* xb  = Qb + n_elem;
    // ws (48MB): [K][V^T][Ab]. Wcat overlays Ab (consumed before attn writes
    // Ab); Wob overlays dead-after-attn K.
    __bf16* Kb   = (__bf16*)d_ws;
    __bf16* Vtb  = Kb + n_elem;
    __bf16* Ab   = Vtb + n_elem;
    __bf16* Wcat = Ab;
    __bf16* Wob  = Kb;

    cvt_x_kernel<<<MTOT * D_MODEL / 1024, 256, 0, stream>>>(x, xb);
    cvt_w3_kernel<<<dim3(w_n / 1024, 3), 256, 0, stream>>>(Wq, Wk, Wv, Wcat);
    qkv_gemm_kernel<<<dim3(24, 64), 256, 0, stream>>>(xb, Wcat, bq, bk, bv,
                                                      Qb, Kb, Vtb);
    attn_kernel<<<dim3(16, 64), 256, 0, stream>>>(Qb, Kb, Vtb, Ab);
    cvt_x_kernel<<<w_n / 1024, 256, 0, stream>>>(Wo, Wob);
    out_gemm_kernel<<<dim3(8, 64), 256, 0, stream>>>(Ab, Wob, bo, out);
}